// Round 15
// baseline (489.605 us; speedup 1.0000x reference)
//
#include <hip/hip_runtime.h>
#include <math.h>

namespace {

constexpr int Bn = 8, CINn = 16, Ln = 256, Dn = 256, Hn = 8, DKn = 32, DVn = 32;
constexpr int KWn = 3, KEn = 5, L4n = 1024;
constexpr float EPSf = 1e-9f;
constexpr int XP = 1040;   // bf16 X-plane pitch (8-col halo each side)
constexpr int LP = 44;     // LDS pitch in ushorts: word-stride 22 -> conv halo staging 4-way (was 8-way at 40)

typedef __attribute__((ext_vector_type(8))) short short8b;
typedef __attribute__((ext_vector_type(4))) float f32x4;

__device__ __forceinline__ float2 cmul(float2 a, float2 b){
  return make_float2(a.x*b.x - a.y*b.y, a.x*b.y + a.y*b.x);
}
__device__ __forceinline__ float2 cfma(float2 a, float2 b, float2 c){
  c.x = fmaf(a.x, b.x, c.x); c.x = fmaf(-a.y, b.y, c.x);
  c.y = fmaf(a.x, b.y, c.y); c.y = fmaf(a.y, b.x, c.y);
  return c;
}
__device__ __forceinline__ ushort f2bf(float f){
  uint u = __float_as_uint(f);
  u += 0x7fffu + ((u >> 16) & 1u);   // RNE
  return (ushort)(u >> 16);
}
__device__ __forceinline__ uint cvt_pk_bf16(float a, float b){
  uint u;
  asm("v_cvt_pk_bf16_f32 %0, %1, %2" : "=v"(u) : "v"(a), "v"(b));
  return u;                           // lo = bf16(a), hi = bf16(b)
}
__device__ __forceinline__ short8b neg8(short8b v){
  union { short8b s; uint u[4]; } x; x.s = v;
  #pragma unroll
  for (int i = 0; i < 4; ++i) x.u[i] ^= 0x80008000u;
  return x.s;
}

// A[b,o,l] = sum_c sum_i X[b,c,l+i-1] * hw[o,c,i] + hb[o]
__global__ void head_conv_kernel(const float2* __restrict__ X, const float2* __restrict__ hw,
                                 const float2* __restrict__ hb, float2* __restrict__ out){
  int idx = blockIdx.x * blockDim.x + threadIdx.x;
  if (idx >= Bn*Dn*Ln) return;
  int l = idx & (Ln-1);
  int o = (idx >> 8) & (Dn-1);
  int b = idx >> 16;
  float2 acc = hb[o];
  for (int c = 0; c < CINn; ++c){
    const float2* xr = X + (size_t)(b*CINn + c)*Ln;
    const float2* wr = hw + (size_t)(o*CINn + c)*KWn;
    #pragma unroll
    for (int i = 0; i < KWn; ++i){
      int ll = l + i - 1;
      if (ll >= 0 && ll < Ln) acc = cfma(xr[ll], wr[i], acc);
    }
  }
  out[idx] = acc;
}

// In-LDS radix-2 FFT; rows mapped through (chans, coff). Optional row-mean out.
template<int N, int LOG>
__global__ void fft_rows_kernel(const float2* __restrict__ src0, float2* __restrict__ dst0,
                                int schans, int scoff, int dchans, int dcoff,
                                float sign, float scale, float2* __restrict__ ysum){
  __shared__ float2 buf[N];
  __shared__ float2 tw[N/2];
  __shared__ float rx[256], ry[256];
  int row = blockIdx.x;
  int rb = row >> 8, rc = row & 255;
  const float2* src = src0 + (size_t)(rb*schans + scoff + rc)*N;
  float2* dst = dst0 + (size_t)(rb*dchans + dcoff + rc)*N;
  int tid = threadIdx.x;
  for (int i = tid; i < N/2; i += 256){
    float a = sign * 6.2831853071795864f * (float)i / (float)N;
    float s, c; __sincosf(a, &s, &c);
    tw[i] = make_float2(c, s);
  }
  for (int i = tid; i < N; i += 256){
    unsigned r = __brev((unsigned)i) >> (32 - LOG);
    buf[r] = src[i];
  }
  __syncthreads();
  for (int st = 1; st <= LOG; ++st){
    int half = 1 << (st-1);
    for (int bf = tid; bf < N/2; bf += 256){
      int blk = bf >> (st-1);
      int pos = bf & (half-1);
      int i0 = (blk << st) + pos;
      int i1 = i0 + half;
      float2 w = tw[pos << (LOG-st)];
      float2 u = buf[i0];
      float2 t = cmul(w, buf[i1]);
      buf[i0] = make_float2(u.x + t.x, u.y + t.y);
      buf[i1] = make_float2(u.x - t.x, u.y - t.y);
    }
    __syncthreads();
  }
  float sx = 0.f, sy = 0.f;
  for (int i = tid; i < N; i += 256){
    float2 o = make_float2(buf[i].x * scale, buf[i].y * scale);
    dst[i] = o; sx += o.x; sy += o.y;
  }
  if (ysum){
    rx[tid] = sx; ry[tid] = sy; __syncthreads();
    for (int st = 128; st > 0; st >>= 1){
      if (tid < st){ rx[tid] += rx[tid+st]; ry[tid] += ry[tid+st]; }
      __syncthreads();
    }
    if (tid == 0)
      ysum[(size_t)rb*dchans + dcoff + rc] = make_float2(rx[0]*(1.f/N), ry[0]*(1.f/N));
  }
}

// mean over rows of 1024, with (chans,coff) mapping on src and dst index space
__global__ void row_mean_map(const float2* __restrict__ src0, int schans, int scoff,
                             float2* __restrict__ y, int dchans, int dcoff){
  int row = blockIdx.x;
  int rb = row >> 8, rc = row & 255;
  const float2* xr = src0 + (size_t)(rb*schans + scoff + rc)*L4n;
  int tid = threadIdx.x;
  float sx = 0.f, sy = 0.f;
  for (int i = tid; i < L4n; i += 256){ float2 v = xr[i]; sx += v.x; sy += v.y; }
  __shared__ float rx[256], ry[256];
  rx[tid] = sx; ry[tid] = sy; __syncthreads();
  for (int st = 128; st > 0; st >>= 1){
    if (tid < st){ rx[tid] += rx[tid+st]; ry[tid] += ry[tid+st]; }
    __syncthreads();
  }
  if (tid == 0)
    y[(size_t)rb*dchans + dcoff + rc] = make_float2(rx[0]*(1.f/L4n), ry[0]*(1.f/L4n));
}

// ---------------- 128x64 complex bf16 MFMA GEMM core (4 waves stacked in m) ----
// cmode 0: out[m*crow+n]; cmode 1: out[n*crow+m] via LDS transpose;
// cmode 2: head-packed bf16; cmode 3: frag-packed bf16.
__device__ __forceinline__ void cgemm_core(
    const ushort* __restrict__ Are, const ushort* __restrict__ Aim, int pitchA, int am0,
    const ushort* __restrict__ Bre, const ushort* __restrict__ Bim, int pitchB, int n0,
    int K, int conv, float2* __restrict__ cbase, size_t crow, int cmode,
    ushort* __restrict__ ore, ushort* __restrict__ oim)
{
  __shared__ ushort sh[16896];           // 192 rows * 44 * 2 planes = 33.8KB; T overlay same size
  ushort* As_re = sh;                    // [128][LP]
  ushort* As_im = sh + 128*LP;           // 5632
  ushort* Bs_re = sh + 256*LP;           // 11264, [64][LP]
  ushort* Bs_im = sh + 320*LP;           // 14080
  int tid = threadIdx.x;
  int lane = tid & 63, w = tid >> 6;
  int lrow = lane & 15, lhalf = lane >> 4;
  f32x4 ar[2][4], ai[2][4];
  #pragma unroll
  for (int s = 0; s < 2; ++s)
    #pragma unroll
    for (int t = 0; t < 4; ++t){ ar[s][t] = (f32x4){0,0,0,0}; ai[s][t] = (f32x4){0,0,0,0}; }
  int nk = K >> 5;
  for (int kc = 0; kc < nk; ++kc){
    int k0 = kc << 5;
    __syncthreads();
    #pragma unroll
    for (int rep = 0; rep < 4; ++rep){
      int q = tid + rep*256;
      int row = q >> 3, kq = (q & 7)*4;
      size_t go = (size_t)(am0 + row)*pitchA + k0 + kq;
      *(uint2*)&As_re[row*LP + kq] = *(const uint2*)&Are[go];
      *(uint2*)&As_im[row*LP + kq] = *(const uint2*)&Aim[go];
    }
    if (!conv){
      #pragma unroll
      for (int rep = 0; rep < 2; ++rep){
        int q = tid + rep*256;
        int row = q >> 3, kq = (q & 7)*4;
        size_t go = (size_t)(n0 + row)*pitchB + k0 + kq;
        *(uint2*)&Bs_re[row*LP + kq] = *(const uint2*)&Bre[go];
        *(uint2*)&Bs_im[row*LP + kq] = *(const uint2*)&Bim[go];
      }
    } else {
      #pragma unroll
      for (int rep = 0; rep < 8; ++rep){
        int idx = tid + rep*256;
        int k = idx >> 6, nn = idx & 63;
        uint kk = (uint)(k0 + k);
        uint c = (kk * 0xAAABu) >> 17;
        int i = (int)(kk - c*3u);
        size_t go = (size_t)c*XP + 8 + n0 + nn + i - 1;
        Bs_re[nn*LP + k] = Bre[go];
        Bs_im[nn*LP + k] = Bim[go];
      }
    }
    __syncthreads();
    short8b afr[2], afi[2], bfr[4], bfi[4];
    #pragma unroll
    for (int s = 0; s < 2; ++s){
      int row = w*32 + s*16 + lrow;
      afr[s] = *(const short8b*)&As_re[row*LP + lhalf*8];
      afi[s] = *(const short8b*)&As_im[row*LP + lhalf*8];
    }
    #pragma unroll
    for (int t = 0; t < 4; ++t){
      int row = t*16 + lrow;
      bfr[t] = *(const short8b*)&Bs_re[row*LP + lhalf*8];
      bfi[t] = *(const short8b*)&Bs_im[row*LP + lhalf*8];
    }
    #pragma unroll
    for (int s = 0; s < 2; ++s){
      short8b ain = neg8(afi[s]);
      #pragma unroll
      for (int t = 0; t < 4; ++t){
        ar[s][t] = __builtin_amdgcn_mfma_f32_16x16x32_bf16(ain,    bfi[t], ar[s][t], 0, 0, 0);
        ar[s][t] = __builtin_amdgcn_mfma_f32_16x16x32_bf16(afr[s], bfr[t], ar[s][t], 0, 0, 0);
        ai[s][t] = __builtin_amdgcn_mfma_f32_16x16x32_bf16(afi[s], bfr[t], ai[s][t], 0, 0, 0);
        ai[s][t] = __builtin_amdgcn_mfma_f32_16x16x32_bf16(afr[s], bfi[t], ai[s][t], 0, 0, 0);
      }
    }
  }
  if (cmode == 0){
    #pragma unroll
    for (int s = 0; s < 2; ++s)
      #pragma unroll
      for (int t = 0; t < 4; ++t)
        #pragma unroll
        for (int r = 0; r < 4; ++r){
          int mm = w*32 + s*16 + lhalf*4 + r;
          int nn = t*16 + lrow;
          if (ore){
            ore[(size_t)mm*crow + nn] = f2bf(ar[s][t][r]);
            oim[(size_t)mm*crow + nn] = f2bf(ai[s][t][r]);
          } else {
            cbase[(size_t)mm*crow + nn] = make_float2(ar[s][t][r], ai[s][t][r]);
          }
        }
  } else if (cmode == 2 || cmode == 3){
    #pragma unroll
    for (int s = 0; s < 2; ++s)
      #pragma unroll
      for (int t = 0; t < 4; ++t)
        #pragma unroll
        for (int r = 0; r < 4; ++r){
          int mm = w*32 + s*16 + lhalf*4 + r;
          int nn = t*16 + lrow;
          int gl = am0 + mm, ge = n0 + nn;
          size_t oidx;
          if (cmode == 2)
            oidx = (((size_t)(ge >> 5))*Ln + gl)*32 + (ge & 31);
          else
            oidx = (((size_t)(ge >> 5))*8 + (gl >> 5))*1024 + (size_t)(ge & 31)*32 + (gl & 31);
          ore[oidx] = f2bf(ar[s][t][r]);
          oim[oidx] = f2bf(ai[s][t][r]);
        }
  } else {
    float2* T = (float2*)sh;               // [128][33] float2 = 16896 ushorts exactly
    #pragma unroll
    for (int h2 = 0; h2 < 2; ++h2){
      __syncthreads();
      #pragma unroll
      for (int s = 0; s < 2; ++s)
        #pragma unroll
        for (int t2 = 0; t2 < 2; ++t2){
          int t = h2*2 + t2;
          #pragma unroll
          for (int r = 0; r < 4; ++r){
            int mm = w*32 + s*16 + lhalf*4 + r;
            int nn = t2*16 + lrow;
            T[mm*33 + nn] = make_float2(ar[s][t][r], ai[s][t][r]);
          }
        }
      __syncthreads();
      #pragma unroll
      for (int rep = 0; rep < 16; ++rep){
        int idx = tid + rep*256;
        int mm = idx & 127, nn = idx >> 7;  // nn 0..31
        float2 v = T[mm*33 + nn];
        if (ore){
          ore[(size_t)(h2*32 + nn)*crow + mm] = f2bf(v.x);
          oim[(size_t)(h2*32 + nn)*crow + mm] = f2bf(v.y);
        } else {
          cbase[(size_t)(h2*32 + nn)*crow + mm] = v;
        }
      }
    }
  }
}

// ---------------- GEMM wrappers ----------------
// Q,K -> head-packed planes [b][h][l][32]; V -> frag-packed [b][h][kc][dv][32].
__global__ __launch_bounds__(256) void qkv_mfma(
    const ushort* __restrict__ aAre, const ushort* __restrict__ aAim,
    const ushort* __restrict__ aBre, const ushort* __restrict__ aBim,
    const ushort* __restrict__ WqRe, const ushort* __restrict__ WqIm,
    const ushort* __restrict__ WkRe, const ushort* __restrict__ WkIm,
    const ushort* __restrict__ WvRe, const ushort* __restrict__ WvIm,
    ushort* __restrict__ QpRe, ushort* __restrict__ QpIm,
    ushort* __restrict__ KpRe, ushort* __restrict__ KpIm,
    ushort* __restrict__ VpRe, ushort* __restrict__ VpIm,
    int set, int m0, size_t pstride)
{
  int my = blockIdx.y;
  int ml = my / 3, which = my - ml*3;
  int m = m0 + ml;
  bool useA = (which == 0) ? (m == 0 || m == 2) : (m == 0 || m == 3);
  const ushort* Are = useA ? aAre : aBre;
  const ushort* Aim = useA ? aAim : aBim;
  const ushort* WRe = (which == 0) ? WqRe : (which == 1) ? WkRe : WvRe;
  const ushort* WIm = (which == 0) ? WqIm : (which == 1) ? WkIm : WvIm;
  size_t woff = (size_t)(set*4 + m)*Dn*Dn;
  int bx = blockIdx.x;
  int nt = bx & 3, mt = (bx >> 2) & 1, b = bx >> 3;
  int l0 = mt*128, e0 = nt*64;
  const ushort* ARe = Are + (size_t)b*Ln*Dn;
  const ushort* AIm = Aim + (size_t)b*Ln*Dn;
  size_t po = (size_t)ml*pstride + (size_t)b*Ln*Dn;
  if (which == 2){
    cgemm_core(ARe, AIm, Dn, l0, WRe + woff, WIm + woff, Dn, e0, Dn, 0,
               nullptr, 0, 3, VpRe + po, VpIm + po);
  } else {
    ushort* orp = ((which == 0) ? QpRe : KpRe) + po;
    ushort* oip = ((which == 0) ? QpIm : KpIm) + po;
    cgemm_core(ARe, AIm, Dn, l0, WRe + woff, WIm + woff, Dn, e0, Dn, 0,
               nullptr, 0, 2, orp, oip);
  }
}

__global__ __launch_bounds__(256) void wo_mfma(
    const ushort* __restrict__ ORe, const ushort* __restrict__ OIm,
    const ushort* __restrict__ WoRe, const ushort* __restrict__ WoIm,
    float2* __restrict__ Xc, int set, int m0)
{
  int ml = blockIdx.y;
  int m = m0 + ml;
  size_t woff = (size_t)(set*4 + m)*Dn*Dn;
  int bx = blockIdx.x;
  int nt = bx & 3, mt = (bx >> 2) & 1, b = bx >> 3;
  int l0 = mt*128, d0 = nt*64;
  const ushort* ARe = ORe + ((size_t)ml*Bn + b)*Ln*Dn;
  const ushort* AIm = OIm + ((size_t)ml*Bn + b)*Ln*Dn;
  float2* cb = Xc + ((size_t)b*Dn + d0)*L4n + m*Ln + l0;
  cgemm_core(ARe, AIm, Dn, l0, WoRe + woff, WoIm + woff, Dn, d0, Dn, 0,
             cb, L4n, 1, nullptr, nullptr);
}

__global__ __launch_bounds__(256) void conv_mfma(
    const ushort* __restrict__ WRe, const ushort* __restrict__ WIm,
    const ushort* __restrict__ XRe, const ushort* __restrict__ XIm,
    float2* __restrict__ out, int ochans)
{
  int bx = blockIdx.x;
  int xt = bx & 15, ot = (bx >> 4) & 1, b = bx >> 5;
  int o0 = ot*128, x0 = xt*64;
  const ushort* xr = XRe + (size_t)b*Dn*XP;
  const ushort* xi = XIm + (size_t)b*Dn*XP;
  float2* cb = out + ((size_t)(b*ochans) + o0)*L4n + x0;
  cgemm_core(WRe, WIm, 768, o0, xr, xi, XP, x0, 768, 1, cb, L4n, 0,
             nullptr, nullptr);
}

// ---------------- MFMA attention (slim structure, coalesced planes) ----------
__global__ __launch_bounds__(256) void attn_mfma(
    const ushort* __restrict__ QRe, const ushort* __restrict__ QIm,
    const ushort* __restrict__ KRe, const ushort* __restrict__ KIm,
    const ushort* __restrict__ VRe, const ushort* __restrict__ VIm,
    ushort* __restrict__ ORe, ushort* __restrict__ OIm, size_t pstride)
{
  size_t po = (size_t)blockIdx.y*pstride;
  const ushort* qre = QRe + po; const ushort* qim = QIm + po;
  const ushort* kre = KRe + po; const ushort* kim = KIm + po;
  const ushort* vre = VRe + po; const ushort* vim = VIm + po;
  ushort* ore = ORe + po; ushort* oim = OIm + po;
  int bx = blockIdx.x;
  int qt = bx >> 6, h = (bx >> 3) & 7, b = bx & 7;
  int q0 = qt*16;
  int tid = threadIdx.x;
  int lane = tid & 63, w = tid >> 6;
  int lg = lane >> 4, lr = lane & 15;
  __shared__ float4 shm4[1056];          // 16896 B carved region
  __shared__ float2 mmb[4][4][4];
  ushort* PsRe = (ushort*)shm4;          // [16][264]
  ushort* PsIm = PsRe + 4224;
  float2* redbuf = (float2*)shm4;        // [4][16][32] = 16384 B overlay
  const float scl = 0.17677669529663687f;
  size_t hbase = (size_t)(b*Hn + h)*Ln*32;

  size_t qoff = hbase + (size_t)(q0 + lr)*32 + lg*8;
  short8b aqr = *(const short8b*)&qre[qoff];
  short8b aqi = *(const short8b*)&qim[qoff];
  short8b aqin = neg8(aqi);

  f32x4 sr[4], si[4];
  #pragma unroll
  for (int t = 0; t < 4; ++t){ sr[t] = (f32x4){0,0,0,0}; si[t] = (f32x4){0,0,0,0}; }
  #pragma unroll
  for (int t = 0; t < 4; ++t){
    int kcol = w*64 + t*16 + lr;
    size_t koff = hbase + (size_t)kcol*32 + lg*8;
    short8b bkr = *(const short8b*)&kre[koff];
    short8b bki = *(const short8b*)&kim[koff];
    sr[t] = __builtin_amdgcn_mfma_f32_16x16x32_bf16(aqin, bki, sr[t], 0, 0, 0);
    sr[t] = __builtin_amdgcn_mfma_f32_16x16x32_bf16(aqr,  bkr, sr[t], 0, 0, 0);
    si[t] = __builtin_amdgcn_mfma_f32_16x16x32_bf16(aqi,  bkr, si[t], 0, 0, 0);
    si[t] = __builtin_amdgcn_mfma_f32_16x16x32_bf16(aqr,  bki, si[t], 0, 0, 0);
  }
  float s2a[4][4];
  float mn2[4], mx2[4];
  #pragma unroll
  for (int r = 0; r < 4; ++r){ mn2[r] = 3.4e38f; mx2[r] = 0.f; }
  #pragma unroll
  for (int t = 0; t < 4; ++t)
    #pragma unroll
    for (int r = 0; r < 4; ++r){
      float x = sr[t][r]*scl, y = si[t][r]*scl;
      sr[t][r] = x; si[t][r] = y;
      float s2 = fmaf(x, x, y*y);
      s2a[t][r] = s2;
      mn2[r] = fminf(mn2[r], s2); mx2[r] = fmaxf(mx2[r], s2);
    }
  #pragma unroll
  for (int off = 1; off < 16; off <<= 1)
    #pragma unroll
    for (int r = 0; r < 4; ++r){
      mn2[r] = fminf(mn2[r], __shfl_xor(mn2[r], off));
      mx2[r] = fmaxf(mx2[r], __shfl_xor(mx2[r], off));
    }
  if (lr == 0){
    #pragma unroll
    for (int r = 0; r < 4; ++r) mmb[w][lg][r] = make_float2(mn2[r], mx2[r]);
  }
  __syncthreads();                       // barrier 1: minmax combine
  float mnv[4], invr[4];
  #pragma unroll
  for (int r = 0; r < 4; ++r){
    float2 v0 = mmb[0][lg][r], v1 = mmb[1][lg][r];
    float2 v2 = mmb[2][lg][r], v3 = mmb[3][lg][r];
    float fmn2 = fminf(fminf(v0.x, v1.x), fminf(v2.x, v3.x));
    float fmx2 = fmaxf(fmaxf(v0.y, v1.y), fmaxf(v2.y, v3.y));
    mnv[r] = sqrtf(fmn2);
    invr[r] = __builtin_amdgcn_rcpf(sqrtf(fmx2) - mnv[r] + EPSf);
  }
  #pragma unroll
  for (int t = 0; t < 4; ++t)
    #pragma unroll
    for (int r = 0; r < 4; ++r){
      int q = lg*4 + r, k = w*64 + t*16 + lr;
      float m = sqrtf(s2a[t][r]);
      float f = (m - mnv[r])*invr[r]*__builtin_amdgcn_rcpf(m + EPSf);
      uint u = cvt_pk_bf16(sr[t][r]*f, si[t][r]*f);
      PsRe[q*264 + k] = (ushort)u;
      PsIm[q*264 + k] = (ushort)(u >> 16);
    }
  // no barrier: PV reads only this wave's own k-columns (same-wave RAW)
  f32x4 pr[2], pi[2];
  #pragma unroll
  for (int t = 0; t < 2; ++t){ pr[t] = (f32x4){0,0,0,0}; pi[t] = (f32x4){0,0,0,0}; }
  #pragma unroll
  for (int kc = 0; kc < 2; ++kc){
    int k0 = w*64 + kc*32;
    short8b par = *(const short8b*)&PsRe[lr*264 + k0 + lg*8];
    short8b pai = *(const short8b*)&PsIm[lr*264 + k0 + lg*8];
    short8b pain = neg8(pai);
    #pragma unroll
    for (int t = 0; t < 2; ++t){
      int dv = t*16 + lr;
      size_t voff = hbase + (size_t)(k0 >> 5)*1024 + dv*32 + lg*8;
      short8b bvr = *(const short8b*)&vre[voff];
      short8b bvi = *(const short8b*)&vim[voff];
      pr[t] = __builtin_amdgcn_mfma_f32_16x16x32_bf16(pain, bvi, pr[t], 0, 0, 0);
      pr[t] = __builtin_amdgcn_mfma_f32_16x16x32_bf16(par,  bvr, pr[t], 0, 0, 0);
      pi[t] = __builtin_amdgcn_mfma_f32_16x16x32_bf16(pai,  bvr, pi[t], 0, 0, 0);
      pi[t] = __builtin_amdgcn_mfma_f32_16x16x32_bf16(par,  bvi, pi[t], 0, 0, 0);
    }
  }
  __syncthreads();                       // barrier 2: all Ps reads done; overlay safe
  #pragma unroll
  for (int t = 0; t < 2; ++t)
    #pragma unroll
    for (int r = 0; r < 4; ++r)
      redbuf[(w*16 + lg*4 + r)*32 + t*16 + lr] = make_float2(pr[t][r], pi[t][r]);
  __syncthreads();                       // barrier 3: redbuf complete
  #pragma unroll
  for (int rep = 0; rep < 2; ++rep){
    int idx = tid + rep*256;
    int q = idx >> 5, dv = idx & 31;
    float2 s0 = redbuf[(0*16 + q)*32 + dv], s1 = redbuf[(1*16 + q)*32 + dv];
    float2 s2 = redbuf[(2*16 + q)*32 + dv], s3 = redbuf[(3*16 + q)*32 + dv];
    float sx = s0.x + s1.x + s2.x + s3.x;
    float sy = s0.y + s1.y + s2.y + s3.y;
    size_t oo = ((size_t)(b*Ln + q0 + q))*Dn + h*DVn + dv;
    uint u = cvt_pk_bf16(sx, sy);
    ore[oo] = (ushort)u; oim[oo] = (ushort)(u >> 16);
  }
}

// ---------------- pack kernels ----------------
__global__ void pack_at(const float2* __restrict__ in, ushort* __restrict__ ore,
                        ushort* __restrict__ oim){
  __shared__ float2 T[32][33];
  int bx = blockIdx.x;
  int lt = bx & 7, dt = (bx >> 3) & 7, b = bx >> 6;
  int tid = threadIdx.x;
  int c = tid & 31, rr = tid >> 5;
  #pragma unroll
  for (int it = 0; it < 4; ++it){
    int d = rr + it*8;
    T[d][c] = in[((size_t)b*Dn + dt*32 + d)*Ln + lt*32 + c];
  }
  __syncthreads();
  #pragma unroll
  for (int it = 0; it < 4; ++it){
    int l = rr + it*8;
    float2 v = T[c][l];
    size_t o = ((size_t)b*Ln + lt*32 + l)*Dn + dt*32 + c;
    ore[o] = f2bf(v.x); oim[o] = f2bf(v.y);
  }
}

// transpose each 256x256 W matrix -> WT[n][k] bf16 planes
__global__ void pack_wt(const float2* __restrict__ wq, const float2* __restrict__ wk,
                        const float2* __restrict__ wv, const float2* __restrict__ wo,
                        ushort* r0, ushort* i0, ushort* r1, ushort* i1,
                        ushort* r2, ushort* i2, ushort* r3, ushort* i3){
  int f = blockIdx.y;
  const float2* in = (f == 0) ? wq : (f == 1) ? wk : (f == 2) ? wv : wo;
  ushort* orr = (f == 0) ? r0 : (f == 1) ? r1 : (f == 2) ? r2 : r3;
  ushort* oii = (f == 0) ? i0 : (f == 1) ? i1 : (f == 2) ? i2 : i3;
  int bx = blockIdx.x;
  int tile = bx & 63, mat = bx >> 6;
  int kt = tile & 7, nt = tile >> 3;
  __shared__ float2 T[32][33];
  int tid = threadIdx.x;
  int c = tid & 31, rr = tid >> 5;
  #pragma unroll
  for (int it = 0; it < 4; ++it){
    int k = rr + it*8;
    T[k][c] = in[((size_t)(mat*256 + kt*32 + k))*256 + nt*32 + c];
  }
  __syncthreads();
  #pragma unroll
  for (int it = 0; it < 4; ++it){
    int n = rr + it*8;
    float2 v = T[c][n];
    size_t o = ((size_t)(mat*256 + nt*32 + n))*256 + kt*32 + c;
    orr[o] = f2bf(v.x); oii[o] = f2bf(v.y);
  }
}

__global__ void pack_sc(const float2* __restrict__ sc, ushort* __restrict__ ore,
                        ushort* __restrict__ oim){
  size_t idx = (size_t)blockIdx.x*256 + threadIdx.x;
  float2 v = sc[idx];
  ore[idx] = f2bf(v.x); oim[idx] = f2bf(v.y);
}

// X *= gate -> bf16 planes with halo
__global__ void eca_apply_pack(const float2* __restrict__ X, const float2* __restrict__ g,
                               ushort* __restrict__ xre, ushort* __restrict__ xim){
  int idx = blockIdx.x*256 + threadIdx.x;
  int row = idx >> 10, x = idx & 1023;
  float2 v = cmul(X[idx], g[row]);
  size_t o = (size_t)row*XP + 8 + x;
  xre[o] = f2bf(v.x); xim[o] = f2bf(v.y);
  if (x < 8){ size_t o2 = (size_t)row*XP + x; xre[o2] = 0; xim[o2] = 0; }
  if (x >= 1016){ size_t o2 = (size_t)row*XP + x + 16; xre[o2] = 0; xim[o2] = 0; }
}

__global__ void eca_gate_kernel(const float2* __restrict__ y, const float2* __restrict__ w,
                                float2* __restrict__ g, int C){
  int idx = blockIdx.x*blockDim.x + threadIdx.x;
  if (idx >= Bn*C) return;
  int c = idx % C;
  int b = idx / C;
  float2 z = make_float2(0.f, 0.f);
  #pragma unroll
  for (int i = 0; i < KEn; ++i){
    int cc = c + i - 2;
    if (cc >= 0 && cc < C) z = cfma(w[i], y[b*C + cc], z);
  }
  g[idx] = make_float2(1.f/(1.f + expf(-z.x)), 1.f/(1.f + expf(-z.y)));
}

// vectorized final gate apply: one float4 (2 complex) per thread
__global__ void eca_apply4(float4* __restrict__ X, const float2* __restrict__ g){
  int idx = blockIdx.x*256 + threadIdx.x;
  int row = idx >> 9;
  float2 gg = g[row];
  float4 v = X[idx];
  float2 a = cmul(make_float2(v.x, v.y), gg);
  float2 b = cmul(make_float2(v.z, v.w), gg);
  X[idx] = make_float4(a.x, a.y, b.x, b.y);
}

} // namespace

extern "C" void kernel_launch(void* const* d_in, const int* in_sizes, int n_in,
                              void* d_out, int out_size, void* d_ws, size_t ws_size,
                              hipStream_t stream){
  const float2* X1 = (const float2*)d_in[0];
  const float2* X2 = (const float2*)d_in[1];
  const float2* head_w = (const float2*)d_in[2];
  const float2* head_b = (const float2*)d_in[3];
  const float2* wq = (const float2*)d_in[4];
  const float2* wk = (const float2*)d_in[5];
  const float2* wv = (const float2*)d_in[6];
  const float2* wo = (const float2*)d_in[7];
  const float2* se = (const float2*)d_in[8];
  const float2* sc = (const float2*)d_in[9];
  const float2* te = (const float2*)d_in[10];

  const size_t SZ_BDL = (size_t)Bn*Dn*Ln;
  const size_t SZ_X   = (size_t)Bn*Dn*L4n;
  const size_t NAt    = (size_t)Bn*Ln*Dn;

  const size_t US_FIX = 2*(4*NAt) + 2*(4*8*(size_t)65536)
                      + 2*(2*(size_t)Dn*768) + 2*((size_t)Bn*Dn*XP);
  auto need_bytes = [&](int mc){
    return (SZ_X + 32768)*sizeof(float2)
         + (US_FIX + (size_t)8*mc*NAt)*sizeof(ushort);
  };
  int mcount = 2;                     // overlay requires mc >= 2
  if (ws_size >= need_bytes(4)) mcount = 4;

  float2* p = (float2*)d_ws;
  float2* Xc = p;  p += SZ_X;
  float2* ybufX = p; p += (size_t)Bn*Dn;
  float2* ybufR = p; p += (size_t)Bn*2*Dn;
  float2* ybufK = p; p += (size_t)Bn*2*Dn;
  float2* gbuf  = p; p += (size_t)Bn*2*Dn;

  ushort* us = (ushort*)p;
  auto grab = [&](size_t n){ ushort* r = us; us += n; return r; };
  ushort *AtRe[4], *AtIm[4];
  for (int i = 0; i < 4; ++i){ AtRe[i] = grab(NAt); AtIm[i] = grab(NAt); }
  ushort *WRe4[4], *WIm4[4];
  for (int f = 0; f < 4; ++f){ WRe4[f] = grab(8*(size_t)65536); WIm4[f] = grab(8*(size_t)65536); }
  ushort* ScRe = grab(2*(size_t)Dn*768);
  ushort* ScIm = grab(2*(size_t)Dn*768);
  ushort* XRe = grab((size_t)Bn*Dn*XP);
  ushort* XIm = grab((size_t)Bn*Dn*XP);
  ushort* QpRe = grab((size_t)mcount*NAt);
  ushort* QpIm = grab((size_t)mcount*NAt);
  ushort* KpRe = grab((size_t)mcount*NAt);
  ushort* KpIm = grab((size_t)mcount*NAt);
  ushort* VpRe = grab((size_t)mcount*NAt);
  ushort* VpIm = grab((size_t)mcount*NAt);
  ushort* ObRe = grab((size_t)mcount*NAt);
  ushort* ObIm = grab((size_t)mcount*NAt);

  // overlay: fp32 head-conv / fft buffers live inside the (not-yet-used) QKVO region
  float2* A  = (float2*)QpRe;
  float2* Bc = A  + SZ_BDL;
  float2* iA = Bc + SZ_BDL;
  float2* iB = iA + SZ_BDL;

  float2* out0 = (float2*)d_out;
  float2* out1 = out0 + (size_t)Bn*2*Dn*L4n;

  head_conv_kernel<<<(Bn*Dn*Ln)/256, 256, 0, stream>>>(X1, head_w, head_b, A);
  head_conv_kernel<<<(Bn*Dn*Ln)/256, 256, 0, stream>>>(
      X2, head_w + (size_t)Dn*CINn*KWn, head_b + Dn, Bc);

  fft_rows_kernel<256,8><<<Bn*Dn, 256, 0, stream>>>(A,  iA, 256,0,256,0, 1.0f, 1.0f/256.0f, nullptr);
  fft_rows_kernel<256,8><<<Bn*Dn, 256, 0, stream>>>(Bc, iB, 256,0,256,0, 1.0f, 1.0f/256.0f, nullptr);

  pack_at<<<512, 256, 0, stream>>>(A,  AtRe[0], AtIm[0]);
  pack_at<<<512, 256, 0, stream>>>(Bc, AtRe[1], AtIm[1]);
  pack_at<<<512, 256, 0, stream>>>(iA, AtRe[2], AtIm[2]);
  pack_at<<<512, 256, 0, stream>>>(iB, AtRe[3], AtIm[3]);
  pack_wt<<<dim3(512, 4), 256, 0, stream>>>(wq, wk, wv, wo,
      WRe4[0], WIm4[0], WRe4[1], WIm4[1], WRe4[2], WIm4[2], WRe4[3], WIm4[3]);
  pack_sc<<<1536, 256, 0, stream>>>(sc, ScRe, ScIm);

  auto run_ssca = [&](int ia, int ib, int set, float2* dstbase, float2* ybufT){
    for (int m0 = 0; m0 < 4; m0 += mcount){
      qkv_mfma<<<dim3(64, 3*mcount), 256, 0, stream>>>(
          AtRe[ia], AtIm[ia], AtRe[ib], AtIm[ib],
          WRe4[0], WIm4[0], WRe4[1], WIm4[1], WRe4[2], WIm4[2],
          QpRe, QpIm, KpRe, KpIm, VpRe, VpIm, set, m0, NAt);
      attn_mfma<<<dim3(Bn*Hn*16, mcount), 256, 0, stream>>>(
          QpRe, QpIm, KpRe, KpIm, VpRe, VpIm, ObRe, ObIm, NAt);
      wo_mfma<<<dim3(64, mcount), 256, 0, stream>>>(
          ObRe, ObIm, WRe4[3], WIm4[3], Xc, set, m0);
    }
    row_mean_map<<<Bn*Dn, 256, 0, stream>>>(Xc, Dn, 0, ybufX, Dn, 0);
    eca_gate_kernel<<<(Bn*Dn + 255)/256, 256, 0, stream>>>(ybufX, se + set*KEn, gbuf, Dn);
    eca_apply_pack<<<(int)(SZ_X/256), 256, 0, stream>>>(Xc, gbuf, XRe, XIm);
    conv_mfma<<<256, 256, 0, stream>>>(
        ScRe + (size_t)set*Dn*768, ScIm + (size_t)set*Dn*768, XRe, XIm, dstbase, 2*Dn);
    row_mean_map<<<Bn*Dn, 256, 0, stream>>>(dstbase, 2*Dn, 0, ybufT, 2*Dn, 0);
  };

  run_ssca(0, 1, 0, out0, ybufR);
  run_ssca(2, 3, 1, out1, ybufK);

  // R2[:,256:] = fft(kk) ; k2[:,256:] = ifft(R)  (+ fused row means)
  fft_rows_kernel<1024,10><<<Bn*Dn, 256, 0, stream>>>(out1, out0, 2*Dn,0, 2*Dn,Dn, -1.0f, 1.0f, ybufR);
  fft_rows_kernel<1024,10><<<Bn*Dn, 256, 0, stream>>>(out0, out1, 2*Dn,0, 2*Dn,Dn, 1.0f, 1.0f/1024.0f, ybufK);

  eca_gate_kernel<<<(Bn*2*Dn + 255)/256, 256, 0, stream>>>(ybufR, te, gbuf, 2*Dn);
  eca_apply4<<<(int)((size_t)Bn*2*Dn*L4n/2/256), 256, 0, stream>>>((float4*)out0, gbuf);
  eca_gate_kernel<<<(Bn*2*Dn + 255)/256, 256, 0, stream>>>(ybufK, te + KEn, gbuf, 2*Dn);
  eca_apply4<<<(int)((size_t)Bn*2*Dn*L4n/2/256), 256, 0, stream>>>((float4*)out1, gbuf);
}

// Round 16
// 364.474 us; speedup vs baseline: 1.3433x; 1.3433x over previous
//
#include <hip/hip_runtime.h>
#include <math.h>

namespace {

constexpr int Bn = 8, CINn = 16, Ln = 256, Dn = 256, Hn = 8, DKn = 32, DVn = 32;
constexpr int KWn = 3, KEn = 5, L4n = 1024;
constexpr float EPSf = 1e-9f;
constexpr int XP = 1040;   // bf16 X-plane pitch (8-col halo each side)
// LP must be multiple of 8 ushorts (16B) so ds_read_b128 fragments stay aligned
// (r15 lesson: LP=44 misaligned b128 -> conv 39->60us despite fewer conflicts).
constexpr int LP = 40;

typedef __attribute__((ext_vector_type(8))) short short8b;
typedef __attribute__((ext_vector_type(4))) float f32x4;

__device__ __forceinline__ float2 cmul(float2 a, float2 b){
  return make_float2(a.x*b.x - a.y*b.y, a.x*b.y + a.y*b.x);
}
__device__ __forceinline__ float2 cfma(float2 a, float2 b, float2 c){
  c.x = fmaf(a.x, b.x, c.x); c.x = fmaf(-a.y, b.y, c.x);
  c.y = fmaf(a.x, b.y, c.y); c.y = fmaf(a.y, b.x, c.y);
  return c;
}
__device__ __forceinline__ ushort f2bf(float f){
  uint u = __float_as_uint(f);
  u += 0x7fffu + ((u >> 16) & 1u);   // RNE
  return (ushort)(u >> 16);
}
__device__ __forceinline__ uint cvt_pk_bf16(float a, float b){
  uint u;
  asm("v_cvt_pk_bf16_f32 %0, %1, %2" : "=v"(u) : "v"(a), "v"(b));
  return u;                           // lo = bf16(a), hi = bf16(b)
}
__device__ __forceinline__ short8b neg8(short8b v){
  union { short8b s; uint u[4]; } x; x.s = v;
  #pragma unroll
  for (int i = 0; i < 4; ++i) x.u[i] ^= 0x80008000u;
  return x.s;
}

// A[b,o,l] = sum_c sum_i X[b,c,l+i-1] * hw[o,c,i] + hb[o]
__global__ void head_conv_kernel(const float2* __restrict__ X, const float2* __restrict__ hw,
                                 const float2* __restrict__ hb, float2* __restrict__ out){
  int idx = blockIdx.x * blockDim.x + threadIdx.x;
  if (idx >= Bn*Dn*Ln) return;
  int l = idx & (Ln-1);
  int o = (idx >> 8) & (Dn-1);
  int b = idx >> 16;
  float2 acc = hb[o];
  for (int c = 0; c < CINn; ++c){
    const float2* xr = X + (size_t)(b*CINn + c)*Ln;
    const float2* wr = hw + (size_t)(o*CINn + c)*KWn;
    #pragma unroll
    for (int i = 0; i < KWn; ++i){
      int ll = l + i - 1;
      if (ll >= 0 && ll < Ln) acc = cfma(xr[ll], wr[i], acc);
    }
  }
  out[idx] = acc;
}

// In-LDS radix-2 FFT; rows mapped through (chans, coff). Optional row-mean out.
template<int N, int LOG>
__global__ void fft_rows_kernel(const float2* __restrict__ src0, float2* __restrict__ dst0,
                                int schans, int scoff, int dchans, int dcoff,
                                float sign, float scale, float2* __restrict__ ysum){
  __shared__ float2 buf[N];
  __shared__ float2 tw[N/2];
  __shared__ float rx[256], ry[256];
  int row = blockIdx.x;
  int rb = row >> 8, rc = row & 255;
  const float2* src = src0 + (size_t)(rb*schans + scoff + rc)*N;
  float2* dst = dst0 + (size_t)(rb*dchans + dcoff + rc)*N;
  int tid = threadIdx.x;
  for (int i = tid; i < N/2; i += 256){
    float a = sign * 6.2831853071795864f * (float)i / (float)N;
    float s, c; __sincosf(a, &s, &c);
    tw[i] = make_float2(c, s);
  }
  for (int i = tid; i < N; i += 256){
    unsigned r = __brev((unsigned)i) >> (32 - LOG);
    buf[r] = src[i];
  }
  __syncthreads();
  for (int st = 1; st <= LOG; ++st){
    int half = 1 << (st-1);
    for (int bf = tid; bf < N/2; bf += 256){
      int blk = bf >> (st-1);
      int pos = bf & (half-1);
      int i0 = (blk << st) + pos;
      int i1 = i0 + half;
      float2 w = tw[pos << (LOG-st)];
      float2 u = buf[i0];
      float2 t = cmul(w, buf[i1]);
      buf[i0] = make_float2(u.x + t.x, u.y + t.y);
      buf[i1] = make_float2(u.x - t.x, u.y - t.y);
    }
    __syncthreads();
  }
  float sx = 0.f, sy = 0.f;
  for (int i = tid; i < N; i += 256){
    float2 o = make_float2(buf[i].x * scale, buf[i].y * scale);
    dst[i] = o; sx += o.x; sy += o.y;
  }
  if (ysum){
    rx[tid] = sx; ry[tid] = sy; __syncthreads();
    for (int st = 128; st > 0; st >>= 1){
      if (tid < st){ rx[tid] += rx[tid+st]; ry[tid] += ry[tid+st]; }
      __syncthreads();
    }
    if (tid == 0)
      ysum[(size_t)rb*dchans + dcoff + rc] = make_float2(rx[0]*(1.f/N), ry[0]*(1.f/N));
  }
}

// mean over rows of 1024, with (chans,coff) mapping on src and dst index space
__global__ void row_mean_map(const float2* __restrict__ src0, int schans, int scoff,
                             float2* __restrict__ y, int dchans, int dcoff){
  int row = blockIdx.x;
  int rb = row >> 8, rc = row & 255;
  const float2* xr = src0 + (size_t)(rb*schans + scoff + rc)*L4n;
  int tid = threadIdx.x;
  float sx = 0.f, sy = 0.f;
  for (int i = tid; i < L4n; i += 256){ float2 v = xr[i]; sx += v.x; sy += v.y; }
  __shared__ float rx[256], ry[256];
  rx[tid] = sx; ry[tid] = sy; __syncthreads();
  for (int st = 128; st > 0; st >>= 1){
    if (tid < st){ rx[tid] += rx[tid+st]; ry[tid] += ry[tid+st]; }
    __syncthreads();
  }
  if (tid == 0)
    y[(size_t)rb*dchans + dcoff + rc] = make_float2(rx[0]*(1.f/L4n), ry[0]*(1.f/L4n));
}

// ---------------- 128x64 complex bf16 MFMA GEMM core (4 waves stacked in m) ----
// cmode 0: out[m*crow+n]; cmode 1: out[n*crow+m] via LDS transpose;
// cmode 2: head-packed bf16; cmode 3: frag-packed bf16.
__device__ __forceinline__ void cgemm_core(
    const ushort* __restrict__ Are, const ushort* __restrict__ Aim, int pitchA, int am0,
    const ushort* __restrict__ Bre, const ushort* __restrict__ Bim, int pitchB, int n0,
    int K, int conv, float2* __restrict__ cbase, size_t crow, int cmode,
    ushort* __restrict__ ore, ushort* __restrict__ oim)
{
  __shared__ ushort sh[16896];           // staging 15360; T overlay 16896 (33.8KB)
  ushort* As_re = sh;                    // [128][LP]
  ushort* As_im = sh + 128*LP;
  ushort* Bs_re = sh + 256*LP;           // [64][LP]
  ushort* Bs_im = sh + 320*LP;
  int tid = threadIdx.x;
  int lane = tid & 63, w = tid >> 6;
  int lrow = lane & 15, lhalf = lane >> 4;
  f32x4 ar[2][4], ai[2][4];
  #pragma unroll
  for (int s = 0; s < 2; ++s)
    #pragma unroll
    for (int t = 0; t < 4; ++t){ ar[s][t] = (f32x4){0,0,0,0}; ai[s][t] = (f32x4){0,0,0,0}; }
  int nk = K >> 5;
  for (int kc = 0; kc < nk; ++kc){
    int k0 = kc << 5;
    __syncthreads();
    #pragma unroll
    for (int rep = 0; rep < 4; ++rep){
      int q = tid + rep*256;
      int row = q >> 3, kq = (q & 7)*4;
      size_t go = (size_t)(am0 + row)*pitchA + k0 + kq;
      *(uint2*)&As_re[row*LP + kq] = *(const uint2*)&Are[go];
      *(uint2*)&As_im[row*LP + kq] = *(const uint2*)&Aim[go];
    }
    if (!conv){
      #pragma unroll
      for (int rep = 0; rep < 2; ++rep){
        int q = tid + rep*256;
        int row = q >> 3, kq = (q & 7)*4;
        size_t go = (size_t)(n0 + row)*pitchB + k0 + kq;
        *(uint2*)&Bs_re[row*LP + kq] = *(const uint2*)&Bre[go];
        *(uint2*)&Bs_im[row*LP + kq] = *(const uint2*)&Bim[go];
      }
    } else {
      #pragma unroll
      for (int rep = 0; rep < 8; ++rep){
        int idx = tid + rep*256;
        int k = idx >> 6, nn = idx & 63;
        uint kk = (uint)(k0 + k);
        uint c = (kk * 0xAAABu) >> 17;
        int i = (int)(kk - c*3u);
        size_t go = (size_t)c*XP + 8 + n0 + nn + i - 1;
        Bs_re[nn*LP + k] = Bre[go];
        Bs_im[nn*LP + k] = Bim[go];
      }
    }
    __syncthreads();
    short8b afr[2], afi[2], bfr[4], bfi[4];
    #pragma unroll
    for (int s = 0; s < 2; ++s){
      int row = w*32 + s*16 + lrow;
      afr[s] = *(const short8b*)&As_re[row*LP + lhalf*8];
      afi[s] = *(const short8b*)&As_im[row*LP + lhalf*8];
    }
    #pragma unroll
    for (int t = 0; t < 4; ++t){
      int row = t*16 + lrow;
      bfr[t] = *(const short8b*)&Bs_re[row*LP + lhalf*8];
      bfi[t] = *(const short8b*)&Bs_im[row*LP + lhalf*8];
    }
    #pragma unroll
    for (int s = 0; s < 2; ++s){
      short8b ain = neg8(afi[s]);
      #pragma unroll
      for (int t = 0; t < 4; ++t){
        ar[s][t] = __builtin_amdgcn_mfma_f32_16x16x32_bf16(ain,    bfi[t], ar[s][t], 0, 0, 0);
        ar[s][t] = __builtin_amdgcn_mfma_f32_16x16x32_bf16(afr[s], bfr[t], ar[s][t], 0, 0, 0);
        ai[s][t] = __builtin_amdgcn_mfma_f32_16x16x32_bf16(afi[s], bfr[t], ai[s][t], 0, 0, 0);
        ai[s][t] = __builtin_amdgcn_mfma_f32_16x16x32_bf16(afr[s], bfi[t], ai[s][t], 0, 0, 0);
      }
    }
  }
  if (cmode == 0){
    #pragma unroll
    for (int s = 0; s < 2; ++s)
      #pragma unroll
      for (int t = 0; t < 4; ++t)
        #pragma unroll
        for (int r = 0; r < 4; ++r){
          int mm = w*32 + s*16 + lhalf*4 + r;
          int nn = t*16 + lrow;
          if (ore){
            ore[(size_t)mm*crow + nn] = f2bf(ar[s][t][r]);
            oim[(size_t)mm*crow + nn] = f2bf(ai[s][t][r]);
          } else {
            cbase[(size_t)mm*crow + nn] = make_float2(ar[s][t][r], ai[s][t][r]);
          }
        }
  } else if (cmode == 2 || cmode == 3){
    #pragma unroll
    for (int s = 0; s < 2; ++s)
      #pragma unroll
      for (int t = 0; t < 4; ++t)
        #pragma unroll
        for (int r = 0; r < 4; ++r){
          int mm = w*32 + s*16 + lhalf*4 + r;
          int nn = t*16 + lrow;
          int gl = am0 + mm, ge = n0 + nn;
          size_t oidx;
          if (cmode == 2)
            oidx = (((size_t)(ge >> 5))*Ln + gl)*32 + (ge & 31);
          else
            oidx = (((size_t)(ge >> 5))*8 + (gl >> 5))*1024 + (size_t)(ge & 31)*32 + (gl & 31);
          ore[oidx] = f2bf(ar[s][t][r]);
          oim[oidx] = f2bf(ai[s][t][r]);
        }
  } else {
    float2* T = (float2*)sh;               // [128][33] float2 = 16896 ushorts exactly
    #pragma unroll
    for (int h2 = 0; h2 < 2; ++h2){
      __syncthreads();
      #pragma unroll
      for (int s = 0; s < 2; ++s)
        #pragma unroll
        for (int t2 = 0; t2 < 2; ++t2){
          int t = h2*2 + t2;
          #pragma unroll
          for (int r = 0; r < 4; ++r){
            int mm = w*32 + s*16 + lhalf*4 + r;
            int nn = t2*16 + lrow;
            T[mm*33 + nn] = make_float2(ar[s][t][r], ai[s][t][r]);
          }
        }
      __syncthreads();
      #pragma unroll
      for (int rep = 0; rep < 16; ++rep){
        int idx = tid + rep*256;
        int mm = idx & 127, nn = idx >> 7;  // nn 0..31
        float2 v = T[mm*33 + nn];
        if (ore){
          ore[(size_t)(h2*32 + nn)*crow + mm] = f2bf(v.x);
          oim[(size_t)(h2*32 + nn)*crow + mm] = f2bf(v.y);
        } else {
          cbase[(size_t)(h2*32 + nn)*crow + mm] = v;
        }
      }
    }
  }
}

// ---------------- GEMM wrappers ----------------
// Q,K -> head-packed planes [b][h][l][32]; V -> frag-packed [b][h][kc][dv][32].
__global__ __launch_bounds__(256) void qkv_mfma(
    const ushort* __restrict__ aAre, const ushort* __restrict__ aAim,
    const ushort* __restrict__ aBre, const ushort* __restrict__ aBim,
    const ushort* __restrict__ WqRe, const ushort* __restrict__ WqIm,
    const ushort* __restrict__ WkRe, const ushort* __restrict__ WkIm,
    const ushort* __restrict__ WvRe, const ushort* __restrict__ WvIm,
    ushort* __restrict__ QpRe, ushort* __restrict__ QpIm,
    ushort* __restrict__ KpRe, ushort* __restrict__ KpIm,
    ushort* __restrict__ VpRe, ushort* __restrict__ VpIm,
    int set, int m0, size_t pstride)
{
  int my = blockIdx.y;
  int ml = my / 3, which = my - ml*3;
  int m = m0 + ml;
  bool useA = (which == 0) ? (m == 0 || m == 2) : (m == 0 || m == 3);
  const ushort* Are = useA ? aAre : aBre;
  const ushort* Aim = useA ? aAim : aBim;
  const ushort* WRe = (which == 0) ? WqRe : (which == 1) ? WkRe : WvRe;
  const ushort* WIm = (which == 0) ? WqIm : (which == 1) ? WkIm : WvIm;
  size_t woff = (size_t)(set*4 + m)*Dn*Dn;
  int bx = blockIdx.x;
  int nt = bx & 3, mt = (bx >> 2) & 1, b = bx >> 3;
  int l0 = mt*128, e0 = nt*64;
  const ushort* ARe = Are + (size_t)b*Ln*Dn;
  const ushort* AIm = Aim + (size_t)b*Ln*Dn;
  size_t po = (size_t)ml*pstride + (size_t)b*Ln*Dn;
  if (which == 2){
    cgemm_core(ARe, AIm, Dn, l0, WRe + woff, WIm + woff, Dn, e0, Dn, 0,
               nullptr, 0, 3, VpRe + po, VpIm + po);
  } else {
    ushort* orp = ((which == 0) ? QpRe : KpRe) + po;
    ushort* oip = ((which == 0) ? QpIm : KpIm) + po;
    cgemm_core(ARe, AIm, Dn, l0, WRe + woff, WIm + woff, Dn, e0, Dn, 0,
               nullptr, 0, 2, orp, oip);
  }
}

__global__ __launch_bounds__(256) void wo_mfma(
    const ushort* __restrict__ ORe, const ushort* __restrict__ OIm,
    const ushort* __restrict__ WoRe, const ushort* __restrict__ WoIm,
    float2* __restrict__ Xc, int set, int m0)
{
  int ml = blockIdx.y;
  int m = m0 + ml;
  size_t woff = (size_t)(set*4 + m)*Dn*Dn;
  int bx = blockIdx.x;
  int nt = bx & 3, mt = (bx >> 2) & 1, b = bx >> 3;
  int l0 = mt*128, d0 = nt*64;
  const ushort* ARe = ORe + ((size_t)ml*Bn + b)*Ln*Dn;
  const ushort* AIm = OIm + ((size_t)ml*Bn + b)*Ln*Dn;
  float2* cb = Xc + ((size_t)b*Dn + d0)*L4n + m*Ln + l0;
  cgemm_core(ARe, AIm, Dn, l0, WoRe + woff, WoIm + woff, Dn, d0, Dn, 0,
             cb, L4n, 1, nullptr, nullptr);
}

// Combined conv for BOTH sets in one launch (grid dim3(256,2)): fixes 1-block/CU
// grid starvation of the single-set 256-block launch.
__global__ __launch_bounds__(256) void conv_mfma2(
    const ushort* __restrict__ ScRe, const ushort* __restrict__ ScIm,
    const ushort* __restrict__ X0Re, const ushort* __restrict__ X0Im,
    const ushort* __restrict__ X1Re, const ushort* __restrict__ X1Im,
    float2* __restrict__ out0, float2* __restrict__ out1, int ochans)
{
  int set = blockIdx.y;
  const ushort* WRe = ScRe + (size_t)set*Dn*768;
  const ushort* WIm = ScIm + (size_t)set*Dn*768;
  const ushort* XRe = set ? X1Re : X0Re;
  const ushort* XIm = set ? X1Im : X0Im;
  float2* dst = set ? out1 : out0;
  int bx = blockIdx.x;
  int xt = bx & 15, ot = (bx >> 4) & 1, b = bx >> 5;
  int o0 = ot*128, x0 = xt*64;
  const ushort* xr = XRe + (size_t)b*Dn*XP;
  const ushort* xi = XIm + (size_t)b*Dn*XP;
  float2* cb = dst + ((size_t)(b*ochans) + o0)*L4n + x0;
  cgemm_core(WRe, WIm, 768, o0, xr, xi, XP, x0, 768, 1, cb, L4n, 0,
             nullptr, nullptr);
}

// ---------------- MFMA attention (slim structure, coalesced planes) ----------
__global__ __launch_bounds__(256) void attn_mfma(
    const ushort* __restrict__ QRe, const ushort* __restrict__ QIm,
    const ushort* __restrict__ KRe, const ushort* __restrict__ KIm,
    const ushort* __restrict__ VRe, const ushort* __restrict__ VIm,
    ushort* __restrict__ ORe, ushort* __restrict__ OIm, size_t pstride)
{
  size_t po = (size_t)blockIdx.y*pstride;
  const ushort* qre = QRe + po; const ushort* qim = QIm + po;
  const ushort* kre = KRe + po; const ushort* kim = KIm + po;
  const ushort* vre = VRe + po; const ushort* vim = VIm + po;
  ushort* ore = ORe + po; ushort* oim = OIm + po;
  int bx = blockIdx.x;
  int qt = bx >> 6, h = (bx >> 3) & 7, b = bx & 7;
  int q0 = qt*16;
  int tid = threadIdx.x;
  int lane = tid & 63, w = tid >> 6;
  int lg = lane >> 4, lr = lane & 15;
  __shared__ float4 shm4[1056];          // 16896 B carved region
  __shared__ float2 mmb[4][4][4];
  ushort* PsRe = (ushort*)shm4;          // [16][264]
  ushort* PsIm = PsRe + 4224;
  float2* redbuf = (float2*)shm4;        // [4][16][32] = 16384 B overlay
  const float scl = 0.17677669529663687f;
  size_t hbase = (size_t)(b*Hn + h)*Ln*32;

  size_t qoff = hbase + (size_t)(q0 + lr)*32 + lg*8;
  short8b aqr = *(const short8b*)&qre[qoff];
  short8b aqi = *(const short8b*)&qim[qoff];
  short8b aqin = neg8(aqi);

  f32x4 sr[4], si[4];
  #pragma unroll
  for (int t = 0; t < 4; ++t){ sr[t] = (f32x4){0,0,0,0}; si[t] = (f32x4){0,0,0,0}; }
  #pragma unroll
  for (int t = 0; t < 4; ++t){
    int kcol = w*64 + t*16 + lr;
    size_t koff = hbase + (size_t)kcol*32 + lg*8;
    short8b bkr = *(const short8b*)&kre[koff];
    short8b bki = *(const short8b*)&kim[koff];
    sr[t] = __builtin_amdgcn_mfma_f32_16x16x32_bf16(aqin, bki, sr[t], 0, 0, 0);
    sr[t] = __builtin_amdgcn_mfma_f32_16x16x32_bf16(aqr,  bkr, sr[t], 0, 0, 0);
    si[t] = __builtin_amdgcn_mfma_f32_16x16x32_bf16(aqi,  bkr, si[t], 0, 0, 0);
    si[t] = __builtin_amdgcn_mfma_f32_16x16x32_bf16(aqr,  bki, si[t], 0, 0, 0);
  }
  float s2a[4][4];
  float mn2[4], mx2[4];
  #pragma unroll
  for (int r = 0; r < 4; ++r){ mn2[r] = 3.4e38f; mx2[r] = 0.f; }
  #pragma unroll
  for (int t = 0; t < 4; ++t)
    #pragma unroll
    for (int r = 0; r < 4; ++r){
      float x = sr[t][r]*scl, y = si[t][r]*scl;
      sr[t][r] = x; si[t][r] = y;
      float s2 = fmaf(x, x, y*y);
      s2a[t][r] = s2;
      mn2[r] = fminf(mn2[r], s2); mx2[r] = fmaxf(mx2[r], s2);
    }
  #pragma unroll
  for (int off = 1; off < 16; off <<= 1)
    #pragma unroll
    for (int r = 0; r < 4; ++r){
      mn2[r] = fminf(mn2[r], __shfl_xor(mn2[r], off));
      mx2[r] = fmaxf(mx2[r], __shfl_xor(mx2[r], off));
    }
  if (lr == 0){
    #pragma unroll
    for (int r = 0; r < 4; ++r) mmb[w][lg][r] = make_float2(mn2[r], mx2[r]);
  }
  __syncthreads();                       // barrier 1: minmax combine
  float mnv[4], invr[4];
  #pragma unroll
  for (int r = 0; r < 4; ++r){
    float2 v0 = mmb[0][lg][r], v1 = mmb[1][lg][r];
    float2 v2 = mmb[2][lg][r], v3 = mmb[3][lg][r];
    float fmn2 = fminf(fminf(v0.x, v1.x), fminf(v2.x, v3.x));
    float fmx2 = fmaxf(fmaxf(v0.y, v1.y), fmaxf(v2.y, v3.y));
    mnv[r] = sqrtf(fmn2);
    invr[r] = __builtin_amdgcn_rcpf(sqrtf(fmx2) - mnv[r] + EPSf);
  }
  #pragma unroll
  for (int t = 0; t < 4; ++t)
    #pragma unroll
    for (int r = 0; r < 4; ++r){
      int q = lg*4 + r, k = w*64 + t*16 + lr;
      float m = sqrtf(s2a[t][r]);
      float f = (m - mnv[r])*invr[r]*__builtin_amdgcn_rcpf(m + EPSf);
      uint u = cvt_pk_bf16(sr[t][r]*f, si[t][r]*f);
      PsRe[q*264 + k] = (ushort)u;
      PsIm[q*264 + k] = (ushort)(u >> 16);
    }
  // no barrier: PV reads only this wave's own k-columns (same-wave RAW)
  f32x4 pr[2], pi[2];
  #pragma unroll
  for (int t = 0; t < 2; ++t){ pr[t] = (f32x4){0,0,0,0}; pi[t] = (f32x4){0,0,0,0}; }
  #pragma unroll
  for (int kc = 0; kc < 2; ++kc){
    int k0 = w*64 + kc*32;
    short8b par = *(const short8b*)&PsRe[lr*264 + k0 + lg*8];
    short8b pai = *(const short8b*)&PsIm[lr*264 + k0 + lg*8];
    short8b pain = neg8(pai);
    #pragma unroll
    for (int t = 0; t < 2; ++t){
      int dv = t*16 + lr;
      size_t voff = hbase + (size_t)(k0 >> 5)*1024 + dv*32 + lg*8;
      short8b bvr = *(const short8b*)&vre[voff];
      short8b bvi = *(const short8b*)&vim[voff];
      pr[t] = __builtin_amdgcn_mfma_f32_16x16x32_bf16(pain, bvi, pr[t], 0, 0, 0);
      pr[t] = __builtin_amdgcn_mfma_f32_16x16x32_bf16(par,  bvr, pr[t], 0, 0, 0);
      pi[t] = __builtin_amdgcn_mfma_f32_16x16x32_bf16(pai,  bvr, pi[t], 0, 0, 0);
      pi[t] = __builtin_amdgcn_mfma_f32_16x16x32_bf16(par,  bvi, pi[t], 0, 0, 0);
    }
  }
  __syncthreads();                       // barrier 2: all Ps reads done; overlay safe
  #pragma unroll
  for (int t = 0; t < 2; ++t)
    #pragma unroll
    for (int r = 0; r < 4; ++r)
      redbuf[(w*16 + lg*4 + r)*32 + t*16 + lr] = make_float2(pr[t][r], pi[t][r]);
  __syncthreads();                       // barrier 3: redbuf complete
  #pragma unroll
  for (int rep = 0; rep < 2; ++rep){
    int idx = tid + rep*256;
    int q = idx >> 5, dv = idx & 31;
    float2 s0 = redbuf[(0*16 + q)*32 + dv], s1 = redbuf[(1*16 + q)*32 + dv];
    float2 s2 = redbuf[(2*16 + q)*32 + dv], s3 = redbuf[(3*16 + q)*32 + dv];
    float sx = s0.x + s1.x + s2.x + s3.x;
    float sy = s0.y + s1.y + s2.y + s3.y;
    size_t oo = ((size_t)(b*Ln + q0 + q))*Dn + h*DVn + dv;
    uint u = cvt_pk_bf16(sx, sy);
    ore[oo] = (ushort)u; oim[oo] = (ushort)(u >> 16);
  }
}

// ---------------- pack kernels ----------------
__global__ void pack_at(const float2* __restrict__ in, ushort* __restrict__ ore,
                        ushort* __restrict__ oim){
  __shared__ float2 T[32][33];
  int bx = blockIdx.x;
  int lt = bx & 7, dt = (bx >> 3) & 7, b = bx >> 6;
  int tid = threadIdx.x;
  int c = tid & 31, rr = tid >> 5;
  #pragma unroll
  for (int it = 0; it < 4; ++it){
    int d = rr + it*8;
    T[d][c] = in[((size_t)b*Dn + dt*32 + d)*Ln + lt*32 + c];
  }
  __syncthreads();
  #pragma unroll
  for (int it = 0; it < 4; ++it){
    int l = rr + it*8;
    float2 v = T[c][l];
    size_t o = ((size_t)b*Ln + lt*32 + l)*Dn + dt*32 + c;
    ore[o] = f2bf(v.x); oim[o] = f2bf(v.y);
  }
}

// transpose each 256x256 W matrix -> WT[n][k] bf16 planes
__global__ void pack_wt(const float2* __restrict__ wq, const float2* __restrict__ wk,
                        const float2* __restrict__ wv, const float2* __restrict__ wo,
                        ushort* r0, ushort* i0, ushort* r1, ushort* i1,
                        ushort* r2, ushort* i2, ushort* r3, ushort* i3){
  int f = blockIdx.y;
  const float2* in = (f == 0) ? wq : (f == 1) ? wk : (f == 2) ? wv : wo;
  ushort* orr = (f == 0) ? r0 : (f == 1) ? r1 : (f == 2) ? r2 : r3;
  ushort* oii = (f == 0) ? i0 : (f == 1) ? i1 : (f == 2) ? i2 : i3;
  int bx = blockIdx.x;
  int tile = bx & 63, mat = bx >> 6;
  int kt = tile & 7, nt = tile >> 3;
  __shared__ float2 T[32][33];
  int tid = threadIdx.x;
  int c = tid & 31, rr = tid >> 5;
  #pragma unroll
  for (int it = 0; it < 4; ++it){
    int k = rr + it*8;
    T[k][c] = in[((size_t)(mat*256 + kt*32 + k))*256 + nt*32 + c];
  }
  __syncthreads();
  #pragma unroll
  for (int it = 0; it < 4; ++it){
    int n = rr + it*8;
    float2 v = T[c][n];
    size_t o = ((size_t)(mat*256 + nt*32 + n))*256 + kt*32 + c;
    orr[o] = f2bf(v.x); oii[o] = f2bf(v.y);
  }
}

__global__ void pack_sc(const float2* __restrict__ sc, ushort* __restrict__ ore,
                        ushort* __restrict__ oim){
  size_t idx = (size_t)blockIdx.x*256 + threadIdx.x;
  float2 v = sc[idx];
  ore[idx] = f2bf(v.x); oim[idx] = f2bf(v.y);
}

// X *= gate -> bf16 planes with halo
__global__ void eca_apply_pack(const float2* __restrict__ X, const float2* __restrict__ g,
                               ushort* __restrict__ xre, ushort* __restrict__ xim){
  int idx = blockIdx.x*256 + threadIdx.x;
  int row = idx >> 10, x = idx & 1023;
  float2 v = cmul(X[idx], g[row]);
  size_t o = (size_t)row*XP + 8 + x;
  xre[o] = f2bf(v.x); xim[o] = f2bf(v.y);
  if (x < 8){ size_t o2 = (size_t)row*XP + x; xre[o2] = 0; xim[o2] = 0; }
  if (x >= 1016){ size_t o2 = (size_t)row*XP + x + 16; xre[o2] = 0; xim[o2] = 0; }
}

__global__ void eca_gate_kernel(const float2* __restrict__ y, const float2* __restrict__ w,
                                float2* __restrict__ g, int C){
  int idx = blockIdx.x*blockDim.x + threadIdx.x;
  if (idx >= Bn*C) return;
  int c = idx % C;
  int b = idx / C;
  float2 z = make_float2(0.f, 0.f);
  #pragma unroll
  for (int i = 0; i < KEn; ++i){
    int cc = c + i - 2;
    if (cc >= 0 && cc < C) z = cfma(w[i], y[b*C + cc], z);
  }
  g[idx] = make_float2(1.f/(1.f + expf(-z.x)), 1.f/(1.f + expf(-z.y)));
}

// vectorized final gate apply: one float4 (2 complex) per thread
__global__ void eca_apply4(float4* __restrict__ X, const float2* __restrict__ g){
  int idx = blockIdx.x*256 + threadIdx.x;
  int row = idx >> 9;
  float2 gg = g[row];
  float4 v = X[idx];
  float2 a = cmul(make_float2(v.x, v.y), gg);
  float2 b = cmul(make_float2(v.z, v.w), gg);
  X[idx] = make_float4(a.x, a.y, b.x, b.y);
}

} // namespace

extern "C" void kernel_launch(void* const* d_in, const int* in_sizes, int n_in,
                              void* d_out, int out_size, void* d_ws, size_t ws_size,
                              hipStream_t stream){
  const float2* X1 = (const float2*)d_in[0];
  const float2* X2 = (const float2*)d_in[1];
  const float2* head_w = (const float2*)d_in[2];
  const float2* head_b = (const float2*)d_in[3];
  const float2* wq = (const float2*)d_in[4];
  const float2* wk = (const float2*)d_in[5];
  const float2* wv = (const float2*)d_in[6];
  const float2* wo = (const float2*)d_in[7];
  const float2* se = (const float2*)d_in[8];
  const float2* sc = (const float2*)d_in[9];
  const float2* te = (const float2*)d_in[10];

  const size_t SZ_BDL = (size_t)Bn*Dn*Ln;
  const size_t SZ_X   = (size_t)Bn*Dn*L4n;
  const size_t NAt    = (size_t)Bn*Ln*Dn;

  const size_t US_FIX = 2*(4*NAt) + 2*(4*8*(size_t)65536)
                      + 2*(2*(size_t)Dn*768) + 4*((size_t)Bn*Dn*XP);   // 2 sets of X planes
  auto need_bytes = [&](int mc){
    return (SZ_X + 32768)*sizeof(float2)
         + (US_FIX + (size_t)8*mc*NAt)*sizeof(ushort);
  };
  int mcount = 2;                     // overlay requires mc >= 2
  if (ws_size >= need_bytes(4)) mcount = 4;

  float2* p = (float2*)d_ws;
  float2* Xc = p;  p += SZ_X;
  float2* ybufX = p; p += (size_t)Bn*Dn;
  float2* ybufR = p; p += (size_t)Bn*2*Dn;
  float2* ybufK = p; p += (size_t)Bn*2*Dn;
  float2* gbuf  = p; p += (size_t)Bn*2*Dn;

  ushort* us = (ushort*)p;
  auto grab = [&](size_t n){ ushort* r = us; us += n; return r; };
  ushort *AtRe[4], *AtIm[4];
  for (int i = 0; i < 4; ++i){ AtRe[i] = grab(NAt); AtIm[i] = grab(NAt); }
  ushort *WRe4[4], *WIm4[4];
  for (int f = 0; f < 4; ++f){ WRe4[f] = grab(8*(size_t)65536); WIm4[f] = grab(8*(size_t)65536); }
  ushort* ScRe = grab(2*(size_t)Dn*768);
  ushort* ScIm = grab(2*(size_t)Dn*768);
  ushort* XRe0 = grab((size_t)Bn*Dn*XP);
  ushort* XIm0 = grab((size_t)Bn*Dn*XP);
  ushort* XRe1 = grab((size_t)Bn*Dn*XP);
  ushort* XIm1 = grab((size_t)Bn*Dn*XP);
  ushort* QpRe = grab((size_t)mcount*NAt);
  ushort* QpIm = grab((size_t)mcount*NAt);
  ushort* KpRe = grab((size_t)mcount*NAt);
  ushort* KpIm = grab((size_t)mcount*NAt);
  ushort* VpRe = grab((size_t)mcount*NAt);
  ushort* VpIm = grab((size_t)mcount*NAt);
  ushort* ObRe = grab((size_t)mcount*NAt);
  ushort* ObIm = grab((size_t)mcount*NAt);

  // overlay: fp32 head-conv / fft buffers live inside the (not-yet-used) QKVO region
  float2* A  = (float2*)QpRe;
  float2* Bc = A  + SZ_BDL;
  float2* iA = Bc + SZ_BDL;
  float2* iB = iA + SZ_BDL;

  float2* out0 = (float2*)d_out;
  float2* out1 = out0 + (size_t)Bn*2*Dn*L4n;

  head_conv_kernel<<<(Bn*Dn*Ln)/256, 256, 0, stream>>>(X1, head_w, head_b, A);
  head_conv_kernel<<<(Bn*Dn*Ln)/256, 256, 0, stream>>>(
      X2, head_w + (size_t)Dn*CINn*KWn, head_b + Dn, Bc);

  fft_rows_kernel<256,8><<<Bn*Dn, 256, 0, stream>>>(A,  iA, 256,0,256,0, 1.0f, 1.0f/256.0f, nullptr);
  fft_rows_kernel<256,8><<<Bn*Dn, 256, 0, stream>>>(Bc, iB, 256,0,256,0, 1.0f, 1.0f/256.0f, nullptr);

  pack_at<<<512, 256, 0, stream>>>(A,  AtRe[0], AtIm[0]);
  pack_at<<<512, 256, 0, stream>>>(Bc, AtRe[1], AtIm[1]);
  pack_at<<<512, 256, 0, stream>>>(iA, AtRe[2], AtIm[2]);
  pack_at<<<512, 256, 0, stream>>>(iB, AtRe[3], AtIm[3]);
  pack_wt<<<dim3(512, 4), 256, 0, stream>>>(wq, wk, wv, wo,
      WRe4[0], WIm4[0], WRe4[1], WIm4[1], WRe4[2], WIm4[2], WRe4[3], WIm4[3]);
  pack_sc<<<1536, 256, 0, stream>>>(sc, ScRe, ScIm);

  // front half of SSCA: projections + attention + Wo + gate + bf16 X planes
  auto ssca_front = [&](int ia, int ib, int set, ushort* xre, ushort* xim){
    for (int m0 = 0; m0 < 4; m0 += mcount){
      qkv_mfma<<<dim3(64, 3*mcount), 256, 0, stream>>>(
          AtRe[ia], AtIm[ia], AtRe[ib], AtIm[ib],
          WRe4[0], WIm4[0], WRe4[1], WIm4[1], WRe4[2], WIm4[2],
          QpRe, QpIm, KpRe, KpIm, VpRe, VpIm, set, m0, NAt);
      attn_mfma<<<dim3(Bn*Hn*16, mcount), 256, 0, stream>>>(
          QpRe, QpIm, KpRe, KpIm, VpRe, VpIm, ObRe, ObIm, NAt);
      wo_mfma<<<dim3(64, mcount), 256, 0, stream>>>(
          ObRe, ObIm, WRe4[3], WIm4[3], Xc, set, m0);
    }
    row_mean_map<<<Bn*Dn, 256, 0, stream>>>(Xc, Dn, 0, ybufX, Dn, 0);
    eca_gate_kernel<<<(Bn*Dn + 255)/256, 256, 0, stream>>>(ybufX, se + set*KEn, gbuf, Dn);
    eca_apply_pack<<<(int)(SZ_X/256), 256, 0, stream>>>(Xc, gbuf, xre, xim);
  };

  ssca_front(0, 1, 0, XRe0, XIm0);
  ssca_front(2, 3, 1, XRe1, XIm1);

  // both sets' convs in ONE launch (512 blocks, 2/CU)
  conv_mfma2<<<dim3(256, 2), 256, 0, stream>>>(
      ScRe, ScIm, XRe0, XIm0, XRe1, XIm1, out0, out1, 2*Dn);

  row_mean_map<<<Bn*Dn, 256, 0, stream>>>(out0, 2*Dn, 0, ybufR, 2*Dn, 0);
  row_mean_map<<<Bn*Dn, 256, 0, stream>>>(out1, 2*Dn, 0, ybufK, 2*Dn, 0);

  // R2[:,256:] = fft(kk) ; k2[:,256:] = ifft(R)  (+ fused row means)
  fft_rows_kernel<1024,10><<<Bn*Dn, 256, 0, stream>>>(out1, out0, 2*Dn,0, 2*Dn,Dn, -1.0f, 1.0f, ybufR);
  fft_rows_kernel<1024,10><<<Bn*Dn, 256, 0, stream>>>(out0, out1, 2*Dn,0, 2*Dn,Dn, 1.0f, 1.0f/1024.0f, ybufK);

  eca_gate_kernel<<<(Bn*2*Dn + 255)/256, 256, 0, stream>>>(ybufR, te, gbuf, 2*Dn);
  eca_apply4<<<(int)((size_t)Bn*2*Dn*L4n/2/256), 256, 0, stream>>>((float4*)out0, gbuf);
  eca_gate_kernel<<<(Bn*2*Dn + 255)/256, 256, 0, stream>>>(ybufK, te + KEn, gbuf, 2*Dn);
  eca_apply4<<<(int)((size_t)Bn*2*Dn*L4n/2/256), 256, 0, stream>>>((float4*)out1, gbuf);
}